// Round 15
// baseline (326.246 us; speedup 1.0000x reference)
//
#include <hip/hip_runtime.h>

typedef unsigned long long u64;

// ---------------- K1a: partial rank counts (no atomics) ----------------
__global__ __launch_bounds__(256)
void k_rank_part(const float* __restrict__ preds, int n, int cpb,
                 int* __restrict__ pc) {
  __shared__ float cs[1024];
  int c0 = blockIdx.y * cpb;
  int cn = min(cpb, n - c0);
  for (int j = threadIdx.x; j < cn; j += blockDim.x)
    cs[j] = preds[(c0 + j) * 5 + 4];
  __syncthreads();
  int i = blockIdx.x * blockDim.x + threadIdx.x;
  if (i >= n) return;
  float ci = preds[i * 5 + 4];
  int cnt = 0;
  const float4* cs4 = (const float4*)cs;
  int cn4 = cn >> 2;
  for (int j4 = 0; j4 < cn4; ++j4) {
    float4 c4 = cs4[j4];
    int jb = c0 + j4 * 4;
    cnt += (c4.x > ci) || (c4.x == ci && (jb + 0) < i);
    cnt += (c4.y > ci) || (c4.y == ci && (jb + 1) < i);
    cnt += (c4.z > ci) || (c4.z == ci && (jb + 2) < i);
    cnt += (c4.w > ci) || (c4.w == ci && (jb + 3) < i);
  }
  for (int j = cn4 * 4; j < cn; ++j)
    cnt += (cs[j] > ci) || (cs[j] == ci && (c0 + j) < i);
  pc[(size_t)blockIdx.y * n + i] = cnt;
}

// ---------------- K1b: sum partials + scatter ----------------
__global__ __launch_bounds__(256)
void k_scatter(const float* __restrict__ preds, const int* __restrict__ pc,
               int n, int nyb, float* __restrict__ sboxes,
               int* __restrict__ sidx) {
  int i = blockIdx.x * blockDim.x + threadIdx.x;
  if (i >= n) return;
  int pos = 0;
  for (int y = 0; y < nyb; ++y) pos += pc[(size_t)y * n + i];
  sboxes[pos * 4 + 0] = preds[i * 5 + 0];
  sboxes[pos * 4 + 1] = preds[i * 5 + 1];
  sboxes[pos * 4 + 2] = preds[i * 5 + 2];
  sboxes[pos * 4 + 3] = preds[i * 5 + 3];
  sidx[pos] = i;
}

// ---------------- K2: suppression bitmask ----------------
// M[row*nw + w] row-major (upper triangle; sub-diagonal words garbage but
// only ever AND into already-consumed scan words).
// D1[row] = M[row][row>>6] (diagonal word): the scan band.
__global__ void k_mask(const float* __restrict__ sboxes, int n,
                       const float* __restrict__ thr_p,
                       u64* __restrict__ M, u64* __restrict__ D1, int nw) {
  int wx = blockIdx.x;  // column word
  int ry = blockIdx.y;  // row group
  if (wx < ry) return;
  int lane = threadIdx.x;

  __shared__ float4 cb[64];
  __shared__ float cbar[64];
  const float4* sb4 = (const float4*)sboxes;
  int col0 = wx * 64;
  int cj = col0 + lane;
  int cjc = cj < n ? cj : n - 1;
  {
    float4 b4 = sb4[cjc];
    cb[lane] = b4;
    cbar[lane] = __fmul_rn(__fsub_rn(b4.z, b4.x), __fsub_rn(b4.w, b4.y));
  }
  __syncthreads();

  int row = ry * 64 + lane;
  if (row >= n) return;
  float th = *thr_p;
  float4 r4 = sb4[row];
  float rarea = __fmul_rn(__fsub_rn(r4.z, r4.x), __fsub_rn(r4.w, r4.y));

  u64 w = 0;
#pragma unroll 8
  for (int j = 0; j < 64; ++j) {
    float4 c4 = cb[j];
    float ix1 = fmaxf(r4.x, c4.x);
    float iy1 = fmaxf(r4.y, c4.y);
    float ix2 = fminf(r4.z, c4.z);
    float iy2 = fminf(r4.w, c4.w);
    float iw = fmaxf(__fsub_rn(ix2, ix1), 0.0f);
    float ih = fmaxf(__fsub_rn(iy2, iy1), 0.0f);
    float inter = __fmul_rn(iw, ih);
    float denom = __fadd_rn(__fsub_rn(__fadd_rn(rarea, cbar[j]), inter), 1e-12f);
    float iou = __fdiv_rn(inter, denom);
    int col = col0 + j;
    bool sup = (col > row) && (col < n) && (iou > th);
    w |= ((u64)sup) << j;
  }
  M[(size_t)row * nw + wx] = w;
  if (wx == ry) D1[row] = w;     // diagonal word
}

// wave-uniform 64-bit broadcast from lane b (uniform) via v_readlane
__device__ __forceinline__ u64 bcast64(u64 v, int b) {
  unsigned lo = __builtin_amdgcn_readlane((unsigned)v, b);
  unsigned hi = __builtin_amdgcn_readlane((unsigned)(v >> 32), b);
  return ((u64)hi << 32) | lo;
}

// extract next pick row (uniform); when exhausted, clamp to chunk base row
#define EXTR1(RV, KX, c)                                                   \
  int RV = (c) * 64 + (KX ? (int)__builtin_ctzll(KX) : 0);                 \
  KX = KX ? (KX & (KX - 1)) : 0;

// issue 16 unconditional row loads into v##P##0..15 (addresses always valid)
#define ISSUE16(P, c)                                                      \
  {                                                                        \
    EXTR1(x0_, kx_, c)  EXTR1(x1_, kx_, c)  EXTR1(x2_, kx_, c)             \
    EXTR1(x3_, kx_, c)  EXTR1(x4_, kx_, c)  EXTR1(x5_, kx_, c)             \
    EXTR1(x6_, kx_, c)  EXTR1(x7_, kx_, c)  EXTR1(x8_, kx_, c)             \
    EXTR1(x9_, kx_, c)  EXTR1(xA_, kx_, c)  EXTR1(xB_, kx_, c)             \
    EXTR1(xC_, kx_, c)  EXTR1(xD_, kx_, c)  EXTR1(xE_, kx_, c)             \
    EXTR1(xF_, kx_, c)                                                     \
    v##P##0 = Mv[(size_t)x0_ * nw2 + lane];                                \
    v##P##1 = Mv[(size_t)x1_ * nw2 + lane];                                \
    v##P##2 = Mv[(size_t)x2_ * nw2 + lane];                                \
    v##P##3 = Mv[(size_t)x3_ * nw2 + lane];                                \
    v##P##4 = Mv[(size_t)x4_ * nw2 + lane];                                \
    v##P##5 = Mv[(size_t)x5_ * nw2 + lane];                                \
    v##P##6 = Mv[(size_t)x6_ * nw2 + lane];                                \
    v##P##7 = Mv[(size_t)x7_ * nw2 + lane];                                \
    v##P##8 = Mv[(size_t)x8_ * nw2 + lane];                                \
    v##P##9 = Mv[(size_t)x9_ * nw2 + lane];                                \
    v##P##10 = Mv[(size_t)xA_ * nw2 + lane];                               \
    v##P##11 = Mv[(size_t)xB_ * nw2 + lane];                               \
    v##P##12 = Mv[(size_t)xC_ * nw2 + lane];                               \
    v##P##13 = Mv[(size_t)xD_ * nw2 + lane];                               \
    v##P##14 = Mv[(size_t)xE_ * nw2 + lane];                               \
    v##P##15 = Mv[(size_t)xF_ * nw2 + lane];                               \
  }

// masked OR of 16 loaded rows into acc (no loads -> no waitcnt hazards)
#define CONSUME16(P, BASE)                                                 \
  acc0 |= ((BASE) + 0 < kc_) ? (v##P##0).x : 0;                            \
  acc1 |= ((BASE) + 0 < kc_) ? (v##P##0).y : 0;                            \
  acc0 |= ((BASE) + 1 < kc_) ? (v##P##1).x : 0;                            \
  acc1 |= ((BASE) + 1 < kc_) ? (v##P##1).y : 0;                            \
  acc0 |= ((BASE) + 2 < kc_) ? (v##P##2).x : 0;                            \
  acc1 |= ((BASE) + 2 < kc_) ? (v##P##2).y : 0;                            \
  acc0 |= ((BASE) + 3 < kc_) ? (v##P##3).x : 0;                            \
  acc1 |= ((BASE) + 3 < kc_) ? (v##P##3).y : 0;                            \
  acc0 |= ((BASE) + 4 < kc_) ? (v##P##4).x : 0;                            \
  acc1 |= ((BASE) + 4 < kc_) ? (v##P##4).y : 0;                            \
  acc0 |= ((BASE) + 5 < kc_) ? (v##P##5).x : 0;                            \
  acc1 |= ((BASE) + 5 < kc_) ? (v##P##5).y : 0;                            \
  acc0 |= ((BASE) + 6 < kc_) ? (v##P##6).x : 0;                            \
  acc1 |= ((BASE) + 6 < kc_) ? (v##P##6).y : 0;                            \
  acc0 |= ((BASE) + 7 < kc_) ? (v##P##7).x : 0;                            \
  acc1 |= ((BASE) + 7 < kc_) ? (v##P##7).y : 0;                            \
  acc0 |= ((BASE) + 8 < kc_) ? (v##P##8).x : 0;                            \
  acc1 |= ((BASE) + 8 < kc_) ? (v##P##8).y : 0;                            \
  acc0 |= ((BASE) + 9 < kc_) ? (v##P##9).x : 0;                            \
  acc1 |= ((BASE) + 9 < kc_) ? (v##P##9).y : 0;                            \
  acc0 |= ((BASE) + 10 < kc_) ? (v##P##10).x : 0;                          \
  acc1 |= ((BASE) + 10 < kc_) ? (v##P##10).y : 0;                          \
  acc0 |= ((BASE) + 11 < kc_) ? (v##P##11).x : 0;                          \
  acc1 |= ((BASE) + 11 < kc_) ? (v##P##11).y : 0;                          \
  acc0 |= ((BASE) + 12 < kc_) ? (v##P##12).x : 0;                          \
  acc1 |= ((BASE) + 12 < kc_) ? (v##P##12).y : 0;                          \
  acc0 |= ((BASE) + 13 < kc_) ? (v##P##13).x : 0;                          \
  acc1 |= ((BASE) + 13 < kc_) ? (v##P##13).y : 0;                          \
  acc0 |= ((BASE) + 14 < kc_) ? (v##P##14).x : 0;                          \
  acc1 |= ((BASE) + 14 < kc_) ? (v##P##14).y : 0;                          \
  acc0 |= ((BASE) + 15 < kc_) ? (v##P##15).x : 0;                          \
  acc1 |= ((BASE) + 15 < kc_) ? (v##P##15).y : 0;

// one 64-box chunk: register-only serial scan (diag band readlanes), sel
// write, then synchronous batched-MLP apply of picked rows, band prefetch.
#define CHUNK(c, BND)                                                      \
  if (out < maxp && (c) < nch) {                                           \
    u64 lw_ = ((c) & 1) ? live1 : live0;                                   \
    u64 rem_ = bcast64(lw_, (c) >> 1);                                     \
    u64 K_ = 0;                                                            \
    int left_ = maxp - out, c2_ = 0;                                       \
    while (rem_) {                                                         \
      int b_ = (int)__builtin_ctzll(rem_);                                 \
      K_ |= (u64)1 << b_;                                                  \
      ++c2_;                                                               \
      if (c2_ >= left_) break;                                             \
      u64 s_ = bcast64(BND, b_);                                           \
      rem_ &= rem_ - 1;                                                    \
      rem_ &= ~s_;                                                         \
    }                                                                      \
    int kc_ = (int)__popcll(K_);                                           \
    if ((K_ >> lane) & 1) {                                                \
      int pos_ = out + (int)__popcll(K_ & (((u64)1 << lane) - 1));         \
      if (pos_ < maxp) sel[pos_] = (c) * 64 + lane;                        \
    }                                                                      \
    out += kc_;                                                            \
    if (kc_ > 0 && out < maxp) {                                           \
      ulonglong2 vA0, vA1, vA2, vA3, vA4, vA5, vA6, vA7;                   \
      ulonglong2 vA8, vA9, vA10, vA11, vA12, vA13, vA14, vA15;             \
      ulonglong2 vB0, vB1, vB2, vB3, vB4, vB5, vB6, vB7;                   \
      ulonglong2 vB8, vB9, vB10, vB11, vB12, vB13, vB14, vB15;             \
      u64 acc0 = 0, acc1 = 0;                                              \
      u64 kx_ = K_;                                                        \
      ISSUE16(A, c)                                                        \
      ISSUE16(B, c)                                                        \
      CONSUME16(A, 0)                                                      \
      if (kc_ > 32) {                                                      \
        ISSUE16(A, c)                                                      \
        CONSUME16(B, 16)                                                   \
        ISSUE16(B, c)                                                      \
        CONSUME16(A, 32)                                                   \
        CONSUME16(B, 48)                                                   \
      } else {                                                             \
        CONSUME16(B, 16)                                                   \
      }                                                                    \
      live0 &= ~acc0;                                                      \
      live1 &= ~acc1;                                                      \
    }                                                                      \
    {                                                                      \
      int cc_ = (c) + 4;                                                   \
      if (cc_ < nch) BND = D1[(size_t)cc_ * 64 + lane];                    \
    }                                                                      \
  }

// ---------------- K3: single-wave greedy scan, batched-MLP apply ----------------
__global__ void k_scan(const u64* __restrict__ M, const u64* __restrict__ D1,
                       int n, int nw, int maxp,
                       int* __restrict__ sel, int* __restrict__ cnt) {
  int lane = threadIdx.x;       // 0..63 (one wave)
  int nch = nw;                 // one 64-box word per chunk
  int nw2 = nw >> 1;
  const ulonglong2* Mv = (const ulonglong2*)M;

  // live words 2*lane and 2*lane+1
  u64 live0, live1;
  {
    int w0 = 2 * lane, w1 = 2 * lane + 1;
    u64 m0 = 0, m1 = 0;
    if (w0 < nw) {
      long long hi = (long long)(w0 + 1) * 64;
      m0 = (hi <= n) ? ~0ULL
                     : ((n > (long long)w0 * 64)
                            ? (((u64)1 << (n - w0 * 64)) - 1) : 0ULL);
    }
    if (w1 < nw) {
      long long hi = (long long)(w1 + 1) * 64;
      m1 = (hi <= n) ? ~0ULL
                     : ((n > (long long)w1 * 64)
                            ? (((u64)1 << (n - w1 * 64)) - 1) : 0ULL);
    }
    live0 = m0; live1 = m1;
  }

  // diag band ring (chunks c..c+3): lane holds D1[c*64+lane]
  u64 b0 = 0, b1 = 0, b2 = 0, b3 = 0;
  if (0 < nch) b0 = D1[(size_t)0 * 64 + lane];
  if (1 < nch) b1 = D1[(size_t)1 * 64 + lane];
  if (2 < nch) b2 = D1[(size_t)2 * 64 + lane];
  if (3 < nch) b3 = D1[(size_t)3 * 64 + lane];

  int out = 0;

  for (int kk = 0; kk < nch && out < maxp; kk += 4) {
    CHUNK(kk + 0, b0)
    CHUNK(kk + 1, b1)
    CHUNK(kk + 2, b2)
    CHUNK(kk + 3, b3)
  }
  if (lane == 0) *cnt = (out < maxp) ? out : maxp;
}

// ---------------- K4: gather outputs ----------------
__global__ void k_emit(const float* __restrict__ preds,
                       const int* __restrict__ sidx,
                       const int* __restrict__ sel,
                       const int* __restrict__ cnt,
                       int maxp, float* __restrict__ out) {
  int k = blockIdx.x * blockDim.x + threadIdx.x;
  if (k >= maxp) return;
  int nk = *cnt;
  if (k < nk) {
    int p = sel[k];
    int orig = sidx[p];
#pragma unroll
    for (int q = 0; q < 5; ++q) out[k * 5 + q] = preds[orig * 5 + q];
    out[(size_t)maxp * 5 + k] = (float)orig;
  } else {
#pragma unroll
    for (int q = 0; q < 5; ++q) out[k * 5 + q] = 0.0f;
    out[(size_t)maxp * 5 + k] = -1.0f;
  }
}

extern "C" void kernel_launch(void* const* d_in, const int* in_sizes, int n_in,
                              void* d_out, int out_size, void* d_ws, size_t ws_size,
                              hipStream_t stream) {
  const float* preds = (const float*)d_in[0];
  const float* thr   = (const float*)d_in[1];
  float* out = (float*)d_out;
  int n    = in_sizes[0] / 5;          // 8192
  int maxp = out_size / 6;             // 1000
  int nw   = (n + 63) / 64;            // 128
  int cpb  = 1024;
  int nyb  = (n + cpb - 1) / cpb;      // 8

  char* ws = (char*)d_ws;
  u64* M = (u64*)ws;
  size_t off = (size_t)n * nw * sizeof(u64);                   // 8 MB
  u64* D1 = (u64*)(ws + off);  off += (size_t)n * sizeof(u64); // 64 KB
  float* sboxes = (float*)(ws + off);  off += (size_t)n * 4 * sizeof(float);
  int*   sidx   = (int*)(ws + off);    off += (size_t)n * sizeof(int);
  int*   sel    = (int*)(ws + off);    off += (size_t)maxp * sizeof(int);
  int*   cnt    = (int*)(ws + off);    off += sizeof(int) * 4;
  int*   pc     = (int*)(ws + off);    // nyb * n ints

  hipLaunchKernelGGL(k_rank_part, dim3((n + 255) / 256, nyb), dim3(256), 0,
                     stream, preds, n, cpb, pc);
  hipLaunchKernelGGL(k_scatter, dim3((n + 255) / 256), dim3(256), 0, stream,
                     preds, pc, n, nyb, sboxes, sidx);
  hipLaunchKernelGGL(k_mask, dim3(nw, nw), dim3(64), 0, stream,
                     sboxes, n, thr, M, D1, nw);
  hipLaunchKernelGGL(k_scan, dim3(1), dim3(64), 0, stream,
                     M, D1, n, nw, maxp, sel, cnt);
  hipLaunchKernelGGL(k_emit, dim3((maxp + 255) / 256), dim3(256), 0, stream,
                     preds, sidx, sel, cnt, maxp, out);
}

// Round 16
// 178.328 us; speedup vs baseline: 1.8295x; 1.8295x over previous
//
#include <hip/hip_runtime.h>

typedef unsigned long long u64;

// ---------------- K1a: partial rank counts (no atomics) ----------------
__global__ __launch_bounds__(256)
void k_rank_part(const float* __restrict__ preds, int n, int cpb,
                 int* __restrict__ pc) {
  __shared__ float cs[1024];
  int c0 = blockIdx.y * cpb;
  int cn = min(cpb, n - c0);
  for (int j = threadIdx.x; j < cn; j += blockDim.x)
    cs[j] = preds[(c0 + j) * 5 + 4];
  __syncthreads();
  int i = blockIdx.x * blockDim.x + threadIdx.x;
  if (i >= n) return;
  float ci = preds[i * 5 + 4];
  int cnt = 0;
  const float4* cs4 = (const float4*)cs;
  int cn4 = cn >> 2;
  for (int j4 = 0; j4 < cn4; ++j4) {
    float4 c4 = cs4[j4];
    int jb = c0 + j4 * 4;
    cnt += (c4.x > ci) || (c4.x == ci && (jb + 0) < i);
    cnt += (c4.y > ci) || (c4.y == ci && (jb + 1) < i);
    cnt += (c4.z > ci) || (c4.z == ci && (jb + 2) < i);
    cnt += (c4.w > ci) || (c4.w == ci && (jb + 3) < i);
  }
  for (int j = cn4 * 4; j < cn; ++j)
    cnt += (cs[j] > ci) || (cs[j] == ci && (c0 + j) < i);
  pc[(size_t)blockIdx.y * n + i] = cnt;
}

// ---------------- K1b: sum partials + scatter ----------------
__global__ __launch_bounds__(256)
void k_scatter(const float* __restrict__ preds, const int* __restrict__ pc,
               int n, int nyb, float* __restrict__ sboxes,
               int* __restrict__ sidx) {
  int i = blockIdx.x * blockDim.x + threadIdx.x;
  if (i >= n) return;
  int pos = 0;
  for (int y = 0; y < nyb; ++y) pos += pc[(size_t)y * n + i];
  sboxes[pos * 4 + 0] = preds[i * 5 + 0];
  sboxes[pos * 4 + 1] = preds[i * 5 + 1];
  sboxes[pos * 4 + 2] = preds[i * 5 + 2];
  sboxes[pos * 4 + 3] = preds[i * 5 + 3];
  sidx[pos] = i;
}

// ---------------- K2: suppression bitmask ----------------
// M[row*nw + w] row-major (upper triangle; sub-diagonal words garbage but
// only ever AND into already-consumed scan words).
// D1[row] = M[row][row>>6] (diagonal word): the scan band.
__global__ void k_mask(const float* __restrict__ sboxes, int n,
                       const float* __restrict__ thr_p,
                       u64* __restrict__ M, u64* __restrict__ D1, int nw) {
  int wx = blockIdx.x;  // column word
  int ry = blockIdx.y;  // row group
  if (wx < ry) return;
  int lane = threadIdx.x;

  __shared__ float4 cb[64];
  __shared__ float cbar[64];
  const float4* sb4 = (const float4*)sboxes;
  int col0 = wx * 64;
  int cj = col0 + lane;
  int cjc = cj < n ? cj : n - 1;
  {
    float4 b4 = sb4[cjc];
    cb[lane] = b4;
    cbar[lane] = __fmul_rn(__fsub_rn(b4.z, b4.x), __fsub_rn(b4.w, b4.y));
  }
  __syncthreads();

  int row = ry * 64 + lane;
  if (row >= n) return;
  float th = *thr_p;
  float4 r4 = sb4[row];
  float rarea = __fmul_rn(__fsub_rn(r4.z, r4.x), __fsub_rn(r4.w, r4.y));

  u64 w = 0;
#pragma unroll 8
  for (int j = 0; j < 64; ++j) {
    float4 c4 = cb[j];
    float ix1 = fmaxf(r4.x, c4.x);
    float iy1 = fmaxf(r4.y, c4.y);
    float ix2 = fminf(r4.z, c4.z);
    float iy2 = fminf(r4.w, c4.w);
    float iw = fmaxf(__fsub_rn(ix2, ix1), 0.0f);
    float ih = fmaxf(__fsub_rn(iy2, iy1), 0.0f);
    float inter = __fmul_rn(iw, ih);
    float denom = __fadd_rn(__fsub_rn(__fadd_rn(rarea, cbar[j]), inter), 1e-12f);
    float iou = __fdiv_rn(inter, denom);
    int col = col0 + j;
    bool sup = (col > row) && (col < n) && (iou > th);
    w |= ((u64)sup) << j;
  }
  M[(size_t)row * nw + wx] = w;
  if (wx == ry) D1[row] = w;     // diagonal word
}

// wave-uniform 64-bit broadcast from lane b (uniform) via v_readlane
__device__ __forceinline__ u64 bcast64(u64 v, int b) {
  unsigned lo = __builtin_amdgcn_readlane((unsigned)v, b);
  unsigned hi = __builtin_amdgcn_readlane((unsigned)(v >> 32), b);
  return ((u64)hi << 32) | lo;
}

// extract next pick row (uniform); when exhausted, clamp to chunk base row
#define EXTR1(RV, KX, c)                                                   \
  int RV = (c) * 64 + (KX ? (int)__builtin_ctzll(KX) : 0);                 \
  KX = KX ? (KX & (KX - 1)) : 0;

// issue 16 unconditional row loads into v##P##0..15 (addresses always valid)
#define ISSUE16(P, c)                                                      \
  {                                                                        \
    EXTR1(x0_, kx_, c)  EXTR1(x1_, kx_, c)  EXTR1(x2_, kx_, c)             \
    EXTR1(x3_, kx_, c)  EXTR1(x4_, kx_, c)  EXTR1(x5_, kx_, c)             \
    EXTR1(x6_, kx_, c)  EXTR1(x7_, kx_, c)  EXTR1(x8_, kx_, c)             \
    EXTR1(x9_, kx_, c)  EXTR1(xA_, kx_, c)  EXTR1(xB_, kx_, c)             \
    EXTR1(xC_, kx_, c)  EXTR1(xD_, kx_, c)  EXTR1(xE_, kx_, c)             \
    EXTR1(xF_, kx_, c)                                                     \
    v##P##0 = Mv[(size_t)x0_ * nw2 + lane];                                \
    v##P##1 = Mv[(size_t)x1_ * nw2 + lane];                                \
    v##P##2 = Mv[(size_t)x2_ * nw2 + lane];                                \
    v##P##3 = Mv[(size_t)x3_ * nw2 + lane];                                \
    v##P##4 = Mv[(size_t)x4_ * nw2 + lane];                                \
    v##P##5 = Mv[(size_t)x5_ * nw2 + lane];                                \
    v##P##6 = Mv[(size_t)x6_ * nw2 + lane];                                \
    v##P##7 = Mv[(size_t)x7_ * nw2 + lane];                                \
    v##P##8 = Mv[(size_t)x8_ * nw2 + lane];                                \
    v##P##9 = Mv[(size_t)x9_ * nw2 + lane];                                \
    v##P##10 = Mv[(size_t)xA_ * nw2 + lane];                               \
    v##P##11 = Mv[(size_t)xB_ * nw2 + lane];                               \
    v##P##12 = Mv[(size_t)xC_ * nw2 + lane];                               \
    v##P##13 = Mv[(size_t)xD_ * nw2 + lane];                               \
    v##P##14 = Mv[(size_t)xE_ * nw2 + lane];                               \
    v##P##15 = Mv[(size_t)xF_ * nw2 + lane];                               \
  }

// masked OR of 16 loaded rows into acc (no loads -> no waitcnt hazards)
#define CONSUME16(P, BASE)                                                 \
  acc0 |= ((BASE) + 0 < kc_) ? (v##P##0).x : 0;                            \
  acc1 |= ((BASE) + 0 < kc_) ? (v##P##0).y : 0;                            \
  acc0 |= ((BASE) + 1 < kc_) ? (v##P##1).x : 0;                            \
  acc1 |= ((BASE) + 1 < kc_) ? (v##P##1).y : 0;                            \
  acc0 |= ((BASE) + 2 < kc_) ? (v##P##2).x : 0;                            \
  acc1 |= ((BASE) + 2 < kc_) ? (v##P##2).y : 0;                            \
  acc0 |= ((BASE) + 3 < kc_) ? (v##P##3).x : 0;                            \
  acc1 |= ((BASE) + 3 < kc_) ? (v##P##3).y : 0;                            \
  acc0 |= ((BASE) + 4 < kc_) ? (v##P##4).x : 0;                            \
  acc1 |= ((BASE) + 4 < kc_) ? (v##P##4).y : 0;                            \
  acc0 |= ((BASE) + 5 < kc_) ? (v##P##5).x : 0;                            \
  acc1 |= ((BASE) + 5 < kc_) ? (v##P##5).y : 0;                            \
  acc0 |= ((BASE) + 6 < kc_) ? (v##P##6).x : 0;                            \
  acc1 |= ((BASE) + 6 < kc_) ? (v##P##6).y : 0;                            \
  acc0 |= ((BASE) + 7 < kc_) ? (v##P##7).x : 0;                            \
  acc1 |= ((BASE) + 7 < kc_) ? (v##P##7).y : 0;                            \
  acc0 |= ((BASE) + 8 < kc_) ? (v##P##8).x : 0;                            \
  acc1 |= ((BASE) + 8 < kc_) ? (v##P##8).y : 0;                            \
  acc0 |= ((BASE) + 9 < kc_) ? (v##P##9).x : 0;                            \
  acc1 |= ((BASE) + 9 < kc_) ? (v##P##9).y : 0;                            \
  acc0 |= ((BASE) + 10 < kc_) ? (v##P##10).x : 0;                          \
  acc1 |= ((BASE) + 10 < kc_) ? (v##P##10).y : 0;                          \
  acc0 |= ((BASE) + 11 < kc_) ? (v##P##11).x : 0;                          \
  acc1 |= ((BASE) + 11 < kc_) ? (v##P##11).y : 0;                          \
  acc0 |= ((BASE) + 12 < kc_) ? (v##P##12).x : 0;                          \
  acc1 |= ((BASE) + 12 < kc_) ? (v##P##12).y : 0;                          \
  acc0 |= ((BASE) + 13 < kc_) ? (v##P##13).x : 0;                          \
  acc1 |= ((BASE) + 13 < kc_) ? (v##P##13).y : 0;                          \
  acc0 |= ((BASE) + 14 < kc_) ? (v##P##14).x : 0;                          \
  acc1 |= ((BASE) + 14 < kc_) ? (v##P##14).y : 0;                          \
  acc0 |= ((BASE) + 15 < kc_) ? (v##P##15).x : 0;                          \
  acc1 |= ((BASE) + 15 < kc_) ? (v##P##15).y : 0;

// one 64-box chunk: register-only serial scan (diag band readlanes), sel
// write, then synchronous batched-MLP apply of picked rows, band prefetch.
#define CHUNK(c, BND)                                                      \
  if (out < maxp && (c) < nch) {                                           \
    u64 lw_ = ((c) & 1) ? live1 : live0;                                   \
    u64 rem_ = bcast64(lw_, (c) >> 1);                                     \
    u64 K_ = 0;                                                            \
    int left_ = maxp - out, c2_ = 0;                                       \
    while (rem_) {                                                         \
      int b_ = (int)__builtin_ctzll(rem_);                                 \
      K_ |= (u64)1 << b_;                                                  \
      ++c2_;                                                               \
      if (c2_ >= left_) break;                                             \
      u64 s_ = bcast64(BND, b_);                                           \
      rem_ &= rem_ - 1;                                                    \
      rem_ &= ~s_;                                                         \
    }                                                                      \
    int kc_ = (int)__popcll(K_);                                           \
    if ((K_ >> lane) & 1) {                                                \
      int pos_ = out + (int)__popcll(K_ & (((u64)1 << lane) - 1));         \
      if (pos_ < maxp) sel[pos_] = (c) * 64 + lane;                        \
    }                                                                      \
    out += kc_;                                                            \
    if (kc_ > 0 && out < maxp) {                                           \
      ulonglong2 vA0, vA1, vA2, vA3, vA4, vA5, vA6, vA7;                   \
      ulonglong2 vA8, vA9, vA10, vA11, vA12, vA13, vA14, vA15;             \
      ulonglong2 vB0, vB1, vB2, vB3, vB4, vB5, vB6, vB7;                   \
      ulonglong2 vB8, vB9, vB10, vB11, vB12, vB13, vB14, vB15;             \
      u64 acc0 = 0, acc1 = 0;                                              \
      u64 kx_ = K_;                                                        \
      ISSUE16(A, c)                                                        \
      ISSUE16(B, c)                                                        \
      CONSUME16(A, 0)                                                      \
      if (kc_ > 32) {                                                      \
        ISSUE16(A, c)                                                      \
        CONSUME16(B, 16)                                                   \
        ISSUE16(B, c)                                                      \
        CONSUME16(A, 32)                                                   \
        CONSUME16(B, 48)                                                   \
      } else {                                                             \
        CONSUME16(B, 16)                                                   \
      }                                                                    \
      live0 &= ~acc0;                                                      \
      live1 &= ~acc1;                                                      \
    }                                                                      \
    {                                                                      \
      int cc_ = (c) + 4;                                                   \
      if (cc_ < nch) BND = D1[(size_t)cc_ * 64 + lane];                    \
    }                                                                      \
  }

// ---------------- K3: single-wave greedy scan, batched-MLP apply ----------------
// __launch_bounds__(64, 1): one wave per block -> VGPR budget 256/thread,
// so the 32 ulonglong2 pick-row buffers (128 VGPRs) stay register-resident
// (round 15's missing bound capped allocation at 64 VGPRs -> scratch spill).
__global__ __launch_bounds__(64, 1)
void k_scan(const u64* __restrict__ M, const u64* __restrict__ D1,
            int n, int nw, int maxp,
            int* __restrict__ sel, int* __restrict__ cnt) {
  int lane = threadIdx.x;       // 0..63 (one wave)
  int nch = nw;                 // one 64-box word per chunk
  int nw2 = nw >> 1;
  const ulonglong2* Mv = (const ulonglong2*)M;

  // live words 2*lane and 2*lane+1
  u64 live0, live1;
  {
    int w0 = 2 * lane, w1 = 2 * lane + 1;
    u64 m0 = 0, m1 = 0;
    if (w0 < nw) {
      long long hi = (long long)(w0 + 1) * 64;
      m0 = (hi <= n) ? ~0ULL
                     : ((n > (long long)w0 * 64)
                            ? (((u64)1 << (n - w0 * 64)) - 1) : 0ULL);
    }
    if (w1 < nw) {
      long long hi = (long long)(w1 + 1) * 64;
      m1 = (hi <= n) ? ~0ULL
                     : ((n > (long long)w1 * 64)
                            ? (((u64)1 << (n - w1 * 64)) - 1) : 0ULL);
    }
    live0 = m0; live1 = m1;
  }

  // diag band ring (chunks c..c+3): lane holds D1[c*64+lane]
  u64 b0 = 0, b1 = 0, b2 = 0, b3 = 0;
  if (0 < nch) b0 = D1[(size_t)0 * 64 + lane];
  if (1 < nch) b1 = D1[(size_t)1 * 64 + lane];
  if (2 < nch) b2 = D1[(size_t)2 * 64 + lane];
  if (3 < nch) b3 = D1[(size_t)3 * 64 + lane];

  int out = 0;

  for (int kk = 0; kk < nch && out < maxp; kk += 4) {
    CHUNK(kk + 0, b0)
    CHUNK(kk + 1, b1)
    CHUNK(kk + 2, b2)
    CHUNK(kk + 3, b3)
  }
  if (lane == 0) *cnt = (out < maxp) ? out : maxp;
}

// ---------------- K4: gather outputs ----------------
__global__ void k_emit(const float* __restrict__ preds,
                       const int* __restrict__ sidx,
                       const int* __restrict__ sel,
                       const int* __restrict__ cnt,
                       int maxp, float* __restrict__ out) {
  int k = blockIdx.x * blockDim.x + threadIdx.x;
  if (k >= maxp) return;
  int nk = *cnt;
  if (k < nk) {
    int p = sel[k];
    int orig = sidx[p];
#pragma unroll
    for (int q = 0; q < 5; ++q) out[k * 5 + q] = preds[orig * 5 + q];
    out[(size_t)maxp * 5 + k] = (float)orig;
  } else {
#pragma unroll
    for (int q = 0; q < 5; ++q) out[k * 5 + q] = 0.0f;
    out[(size_t)maxp * 5 + k] = -1.0f;
  }
}

extern "C" void kernel_launch(void* const* d_in, const int* in_sizes, int n_in,
                              void* d_out, int out_size, void* d_ws, size_t ws_size,
                              hipStream_t stream) {
  const float* preds = (const float*)d_in[0];
  const float* thr   = (const float*)d_in[1];
  float* out = (float*)d_out;
  int n    = in_sizes[0] / 5;          // 8192
  int maxp = out_size / 6;             // 1000
  int nw   = (n + 63) / 64;            // 128
  int cpb  = 1024;
  int nyb  = (n + cpb - 1) / cpb;      // 8

  char* ws = (char*)d_ws;
  u64* M = (u64*)ws;
  size_t off = (size_t)n * nw * sizeof(u64);                   // 8 MB
  u64* D1 = (u64*)(ws + off);  off += (size_t)n * sizeof(u64); // 64 KB
  float* sboxes = (float*)(ws + off);  off += (size_t)n * 4 * sizeof(float);
  int*   sidx   = (int*)(ws + off);    off += (size_t)n * sizeof(int);
  int*   sel    = (int*)(ws + off);    off += (size_t)maxp * sizeof(int);
  int*   cnt    = (int*)(ws + off);    off += sizeof(int) * 4;
  int*   pc     = (int*)(ws + off);    // nyb * n ints

  hipLaunchKernelGGL(k_rank_part, dim3((n + 255) / 256, nyb), dim3(256), 0,
                     stream, preds, n, cpb, pc);
  hipLaunchKernelGGL(k_scatter, dim3((n + 255) / 256), dim3(256), 0, stream,
                     preds, pc, n, nyb, sboxes, sidx);
  hipLaunchKernelGGL(k_mask, dim3(nw, nw), dim3(64), 0, stream,
                     sboxes, n, thr, M, D1, nw);
  hipLaunchKernelGGL(k_scan, dim3(1), dim3(64), 0, stream,
                     M, D1, n, nw, maxp, sel, cnt);
  hipLaunchKernelGGL(k_emit, dim3((maxp + 255) / 256), dim3(256), 0, stream,
                     preds, sidx, sel, cnt, maxp, out);
}

// Round 17
// 178.136 us; speedup vs baseline: 1.8314x; 1.0011x over previous
//
#include <hip/hip_runtime.h>

typedef unsigned long long u64;

// ---------------- K1a: partial rank counts (no atomics) ----------------
__global__ __launch_bounds__(256)
void k_rank_part(const float* __restrict__ preds, int n, int cpb,
                 int* __restrict__ pc) {
  __shared__ float cs[1024];
  int c0 = blockIdx.y * cpb;
  int cn = min(cpb, n - c0);
  for (int j = threadIdx.x; j < cn; j += blockDim.x)
    cs[j] = preds[(c0 + j) * 5 + 4];
  __syncthreads();
  int i = blockIdx.x * blockDim.x + threadIdx.x;
  if (i >= n) return;
  float ci = preds[i * 5 + 4];
  int cnt = 0;
  const float4* cs4 = (const float4*)cs;
  int cn4 = cn >> 2;
  for (int j4 = 0; j4 < cn4; ++j4) {
    float4 c4 = cs4[j4];
    int jb = c0 + j4 * 4;
    cnt += (c4.x > ci) || (c4.x == ci && (jb + 0) < i);
    cnt += (c4.y > ci) || (c4.y == ci && (jb + 1) < i);
    cnt += (c4.z > ci) || (c4.z == ci && (jb + 2) < i);
    cnt += (c4.w > ci) || (c4.w == ci && (jb + 3) < i);
  }
  for (int j = cn4 * 4; j < cn; ++j)
    cnt += (cs[j] > ci) || (cs[j] == ci && (c0 + j) < i);
  pc[(size_t)blockIdx.y * n + i] = cnt;
}

// ---------------- K1b: sum partials + scatter ----------------
__global__ __launch_bounds__(256)
void k_scatter(const float* __restrict__ preds, const int* __restrict__ pc,
               int n, int nyb, float* __restrict__ sboxes,
               int* __restrict__ sidx) {
  int i = blockIdx.x * blockDim.x + threadIdx.x;
  if (i >= n) return;
  int pos = 0;
  for (int y = 0; y < nyb; ++y) pos += pc[(size_t)y * n + i];
  sboxes[pos * 4 + 0] = preds[i * 5 + 0];
  sboxes[pos * 4 + 1] = preds[i * 5 + 1];
  sboxes[pos * 4 + 2] = preds[i * 5 + 2];
  sboxes[pos * 4 + 3] = preds[i * 5 + 3];
  sidx[pos] = i;
}

// ---------------- K2: suppression bitmask ----------------
// M[row*nw + w] row-major (upper triangle; sub-diagonal words garbage but
// only ever AND into already-consumed scan words).
// D1[row] = M[row][row>>6] (diagonal word): the scan band.
__global__ void k_mask(const float* __restrict__ sboxes, int n,
                       const float* __restrict__ thr_p,
                       u64* __restrict__ M, u64* __restrict__ D1, int nw) {
  int wx = blockIdx.x;  // column word
  int ry = blockIdx.y;  // row group
  if (wx < ry) return;
  int lane = threadIdx.x;

  __shared__ float4 cb[64];
  __shared__ float cbar[64];
  const float4* sb4 = (const float4*)sboxes;
  int col0 = wx * 64;
  int cj = col0 + lane;
  int cjc = cj < n ? cj : n - 1;
  {
    float4 b4 = sb4[cjc];
    cb[lane] = b4;
    cbar[lane] = __fmul_rn(__fsub_rn(b4.z, b4.x), __fsub_rn(b4.w, b4.y));
  }
  __syncthreads();

  int row = ry * 64 + lane;
  if (row >= n) return;
  float th = *thr_p;
  float4 r4 = sb4[row];
  float rarea = __fmul_rn(__fsub_rn(r4.z, r4.x), __fsub_rn(r4.w, r4.y));

  u64 w = 0;
#pragma unroll 8
  for (int j = 0; j < 64; ++j) {
    float4 c4 = cb[j];
    float ix1 = fmaxf(r4.x, c4.x);
    float iy1 = fmaxf(r4.y, c4.y);
    float ix2 = fminf(r4.z, c4.z);
    float iy2 = fminf(r4.w, c4.w);
    float iw = fmaxf(__fsub_rn(ix2, ix1), 0.0f);
    float ih = fmaxf(__fsub_rn(iy2, iy1), 0.0f);
    float inter = __fmul_rn(iw, ih);
    float denom = __fadd_rn(__fsub_rn(__fadd_rn(rarea, cbar[j]), inter), 1e-12f);
    float iou = __fdiv_rn(inter, denom);
    int col = col0 + j;
    bool sup = (col > row) && (col < n) && (iou > th);
    w |= ((u64)sup) << j;
  }
  M[(size_t)row * nw + wx] = w;
  if (wx == ry) D1[row] = w;     // diagonal word
}

// wave-uniform 64-bit broadcast from SGPR lane index b (single v_readlane pair)
__device__ __forceinline__ u64 bcast64(u64 v, int b) {
  unsigned lo = __builtin_amdgcn_readlane((unsigned)v, b);
  unsigned hi = __builtin_amdgcn_readlane((unsigned)(v >> 32), b);
  return ((u64)hi << 32) | lo;
}

// force a wave-uniform 64-bit value into scalar registers (SALU chain enabler)
__device__ __forceinline__ u64 sgpr64(u64 v) {
  unsigned lo = __builtin_amdgcn_readfirstlane((unsigned)v);
  unsigned hi = __builtin_amdgcn_readfirstlane((unsigned)(v >> 32));
  return ((u64)hi << 32) | lo;
}

// extract next pick row (uniform); when exhausted, clamp to chunk base row
#define EXTR1(RV, KX, c)                                                   \
  int RV = (c) * 64 + (KX ? (int)__builtin_ctzll(KX) : 0);                 \
  KX = KX ? (KX & (KX - 1)) : 0;

// issue 16 unconditional row loads into v##P##0..15 (addresses always valid)
#define ISSUE16(P, c)                                                      \
  {                                                                        \
    EXTR1(x0_, kx_, c)  EXTR1(x1_, kx_, c)  EXTR1(x2_, kx_, c)             \
    EXTR1(x3_, kx_, c)  EXTR1(x4_, kx_, c)  EXTR1(x5_, kx_, c)             \
    EXTR1(x6_, kx_, c)  EXTR1(x7_, kx_, c)  EXTR1(x8_, kx_, c)             \
    EXTR1(x9_, kx_, c)  EXTR1(xA_, kx_, c)  EXTR1(xB_, kx_, c)             \
    EXTR1(xC_, kx_, c)  EXTR1(xD_, kx_, c)  EXTR1(xE_, kx_, c)             \
    EXTR1(xF_, kx_, c)                                                     \
    v##P##0 = Mv[(size_t)x0_ * nw2 + lane];                                \
    v##P##1 = Mv[(size_t)x1_ * nw2 + lane];                                \
    v##P##2 = Mv[(size_t)x2_ * nw2 + lane];                                \
    v##P##3 = Mv[(size_t)x3_ * nw2 + lane];                                \
    v##P##4 = Mv[(size_t)x4_ * nw2 + lane];                                \
    v##P##5 = Mv[(size_t)x5_ * nw2 + lane];                                \
    v##P##6 = Mv[(size_t)x6_ * nw2 + lane];                                \
    v##P##7 = Mv[(size_t)x7_ * nw2 + lane];                                \
    v##P##8 = Mv[(size_t)x8_ * nw2 + lane];                                \
    v##P##9 = Mv[(size_t)x9_ * nw2 + lane];                                \
    v##P##10 = Mv[(size_t)xA_ * nw2 + lane];                               \
    v##P##11 = Mv[(size_t)xB_ * nw2 + lane];                               \
    v##P##12 = Mv[(size_t)xC_ * nw2 + lane];                               \
    v##P##13 = Mv[(size_t)xD_ * nw2 + lane];                               \
    v##P##14 = Mv[(size_t)xE_ * nw2 + lane];                               \
    v##P##15 = Mv[(size_t)xF_ * nw2 + lane];                               \
  }

// masked OR of 16 loaded rows into acc (no loads -> no waitcnt hazards)
#define CONSUME16(P, BASE)                                                 \
  acc0 |= ((BASE) + 0 < kc_) ? (v##P##0).x : 0;                            \
  acc1 |= ((BASE) + 0 < kc_) ? (v##P##0).y : 0;                            \
  acc0 |= ((BASE) + 1 < kc_) ? (v##P##1).x : 0;                            \
  acc1 |= ((BASE) + 1 < kc_) ? (v##P##1).y : 0;                            \
  acc0 |= ((BASE) + 2 < kc_) ? (v##P##2).x : 0;                            \
  acc1 |= ((BASE) + 2 < kc_) ? (v##P##2).y : 0;                            \
  acc0 |= ((BASE) + 3 < kc_) ? (v##P##3).x : 0;                            \
  acc1 |= ((BASE) + 3 < kc_) ? (v##P##3).y : 0;                            \
  acc0 |= ((BASE) + 4 < kc_) ? (v##P##4).x : 0;                            \
  acc1 |= ((BASE) + 4 < kc_) ? (v##P##4).y : 0;                            \
  acc0 |= ((BASE) + 5 < kc_) ? (v##P##5).x : 0;                            \
  acc1 |= ((BASE) + 5 < kc_) ? (v##P##5).y : 0;                            \
  acc0 |= ((BASE) + 6 < kc_) ? (v##P##6).x : 0;                            \
  acc1 |= ((BASE) + 6 < kc_) ? (v##P##6).y : 0;                            \
  acc0 |= ((BASE) + 7 < kc_) ? (v##P##7).x : 0;                            \
  acc1 |= ((BASE) + 7 < kc_) ? (v##P##7).y : 0;                            \
  acc0 |= ((BASE) + 8 < kc_) ? (v##P##8).x : 0;                            \
  acc1 |= ((BASE) + 8 < kc_) ? (v##P##8).y : 0;                            \
  acc0 |= ((BASE) + 9 < kc_) ? (v##P##9).x : 0;                            \
  acc1 |= ((BASE) + 9 < kc_) ? (v##P##9).y : 0;                            \
  acc0 |= ((BASE) + 10 < kc_) ? (v##P##10).x : 0;                          \
  acc1 |= ((BASE) + 10 < kc_) ? (v##P##10).y : 0;                          \
  acc0 |= ((BASE) + 11 < kc_) ? (v##P##11).x : 0;                          \
  acc1 |= ((BASE) + 11 < kc_) ? (v##P##11).y : 0;                          \
  acc0 |= ((BASE) + 12 < kc_) ? (v##P##12).x : 0;                          \
  acc1 |= ((BASE) + 12 < kc_) ? (v##P##12).y : 0;                          \
  acc0 |= ((BASE) + 13 < kc_) ? (v##P##13).x : 0;                          \
  acc1 |= ((BASE) + 13 < kc_) ? (v##P##13).y : 0;                          \
  acc0 |= ((BASE) + 14 < kc_) ? (v##P##14).x : 0;                          \
  acc1 |= ((BASE) + 14 < kc_) ? (v##P##14).y : 0;                          \
  acc0 |= ((BASE) + 15 < kc_) ? (v##P##15).x : 0;                          \
  acc1 |= ((BASE) + 15 < kc_) ? (v##P##15).y : 0;

// one 64-box chunk: SCALAR serial scan (rem_/K_ in SGPRs -> s_ff1/s_andn2
// chain + single-instruction readlanes), sel write, then synchronous
// batched-MLP apply of picked rows, band prefetch.
#define CHUNK(c, BND)                                                      \
  if (out < maxp && (c) < nch) {                                           \
    u64 lw_ = ((c) & 1) ? live1 : live0;                                   \
    u64 rem_ = sgpr64(bcast64(lw_, (c) >> 1));                             \
    u64 K_ = 0;                                                            \
    int left_ = maxp - out, c2_ = 0;                                       \
    while (rem_) {                                                         \
      int b_ = __builtin_amdgcn_readfirstlane((int)__builtin_ctzll(rem_)); \
      K_ |= (u64)1 << b_;                                                  \
      ++c2_;                                                               \
      if (c2_ >= left_) break;                                             \
      u64 s_ = bcast64(BND, b_);                                           \
      rem_ &= rem_ - 1;                                                    \
      rem_ &= ~s_;                                                         \
    }                                                                      \
    int kc_ = (int)__popcll(K_);                                           \
    if ((K_ >> lane) & 1) {                                                \
      int pos_ = out + (int)__popcll(K_ & (((u64)1 << lane) - 1));         \
      if (pos_ < maxp) sel[pos_] = (c) * 64 + lane;                        \
    }                                                                      \
    out += kc_;                                                            \
    if (kc_ > 0 && out < maxp) {                                           \
      ulonglong2 vA0, vA1, vA2, vA3, vA4, vA5, vA6, vA7;                   \
      ulonglong2 vA8, vA9, vA10, vA11, vA12, vA13, vA14, vA15;             \
      ulonglong2 vB0, vB1, vB2, vB3, vB4, vB5, vB6, vB7;                   \
      ulonglong2 vB8, vB9, vB10, vB11, vB12, vB13, vB14, vB15;             \
      u64 acc0 = 0, acc1 = 0;                                              \
      u64 kx_ = K_;                                                        \
      ISSUE16(A, c)                                                        \
      ISSUE16(B, c)                                                        \
      CONSUME16(A, 0)                                                      \
      if (kc_ > 32) {                                                      \
        ISSUE16(A, c)                                                      \
        CONSUME16(B, 16)                                                   \
        ISSUE16(B, c)                                                      \
        CONSUME16(A, 32)                                                   \
        CONSUME16(B, 48)                                                   \
      } else {                                                             \
        CONSUME16(B, 16)                                                   \
      }                                                                    \
      live0 &= ~acc0;                                                      \
      live1 &= ~acc1;                                                      \
    }                                                                      \
    {                                                                      \
      int cc_ = (c) + 4;                                                   \
      if (cc_ < nch) BND = D1[(size_t)cc_ * 64 + lane];                    \
    }                                                                      \
  }

// ---------------- K3: single-wave greedy scan, batched-MLP apply ----------------
// __launch_bounds__(64, 1): one wave -> 256-VGPR budget; 32 ulonglong2
// pick-row buffers stay register-resident (round 16's fix, VGPR=112).
__global__ __launch_bounds__(64, 1)
void k_scan(const u64* __restrict__ M, const u64* __restrict__ D1,
            int n, int nw, int maxp,
            int* __restrict__ sel, int* __restrict__ cnt) {
  int lane = threadIdx.x;       // 0..63 (one wave)
  int nch = nw;                 // one 64-box word per chunk
  int nw2 = nw >> 1;
  const ulonglong2* Mv = (const ulonglong2*)M;

  // live words 2*lane and 2*lane+1
  u64 live0, live1;
  {
    int w0 = 2 * lane, w1 = 2 * lane + 1;
    u64 m0 = 0, m1 = 0;
    if (w0 < nw) {
      long long hi = (long long)(w0 + 1) * 64;
      m0 = (hi <= n) ? ~0ULL
                     : ((n > (long long)w0 * 64)
                            ? (((u64)1 << (n - w0 * 64)) - 1) : 0ULL);
    }
    if (w1 < nw) {
      long long hi = (long long)(w1 + 1) * 64;
      m1 = (hi <= n) ? ~0ULL
                     : ((n > (long long)w1 * 64)
                            ? (((u64)1 << (n - w1 * 64)) - 1) : 0ULL);
    }
    live0 = m0; live1 = m1;
  }

  // diag band ring (chunks c..c+3): lane holds D1[c*64+lane]
  u64 b0 = 0, b1 = 0, b2 = 0, b3 = 0;
  if (0 < nch) b0 = D1[(size_t)0 * 64 + lane];
  if (1 < nch) b1 = D1[(size_t)1 * 64 + lane];
  if (2 < nch) b2 = D1[(size_t)2 * 64 + lane];
  if (3 < nch) b3 = D1[(size_t)3 * 64 + lane];

  int out = 0;

  for (int kk = 0; kk < nch && out < maxp; kk += 4) {
    CHUNK(kk + 0, b0)
    CHUNK(kk + 1, b1)
    CHUNK(kk + 2, b2)
    CHUNK(kk + 3, b3)
  }
  if (lane == 0) *cnt = (out < maxp) ? out : maxp;
}

// ---------------- K4: gather outputs ----------------
__global__ void k_emit(const float* __restrict__ preds,
                       const int* __restrict__ sidx,
                       const int* __restrict__ sel,
                       const int* __restrict__ cnt,
                       int maxp, float* __restrict__ out) {
  int k = blockIdx.x * blockDim.x + threadIdx.x;
  if (k >= maxp) return;
  int nk = *cnt;
  if (k < nk) {
    int p = sel[k];
    int orig = sidx[p];
#pragma unroll
    for (int q = 0; q < 5; ++q) out[k * 5 + q] = preds[orig * 5 + q];
    out[(size_t)maxp * 5 + k] = (float)orig;
  } else {
#pragma unroll
    for (int q = 0; q < 5; ++q) out[k * 5 + q] = 0.0f;
    out[(size_t)maxp * 5 + k] = -1.0f;
  }
}

extern "C" void kernel_launch(void* const* d_in, const int* in_sizes, int n_in,
                              void* d_out, int out_size, void* d_ws, size_t ws_size,
                              hipStream_t stream) {
  const float* preds = (const float*)d_in[0];
  const float* thr   = (const float*)d_in[1];
  float* out = (float*)d_out;
  int n    = in_sizes[0] / 5;          // 8192
  int maxp = out_size / 6;             // 1000
  int nw   = (n + 63) / 64;            // 128
  int cpb  = 1024;
  int nyb  = (n + cpb - 1) / cpb;      // 8

  char* ws = (char*)d_ws;
  u64* M = (u64*)ws;
  size_t off = (size_t)n * nw * sizeof(u64);                   // 8 MB
  u64* D1 = (u64*)(ws + off);  off += (size_t)n * sizeof(u64); // 64 KB
  float* sboxes = (float*)(ws + off);  off += (size_t)n * 4 * sizeof(float);
  int*   sidx   = (int*)(ws + off);    off += (size_t)n * sizeof(int);
  int*   sel    = (int*)(ws + off);    off += (size_t)maxp * sizeof(int);
  int*   cnt    = (int*)(ws + off);    off += sizeof(int) * 4;
  int*   pc     = (int*)(ws + off);    // nyb * n ints

  hipLaunchKernelGGL(k_rank_part, dim3((n + 255) / 256, nyb), dim3(256), 0,
                     stream, preds, n, cpb, pc);
  hipLaunchKernelGGL(k_scatter, dim3((n + 255) / 256), dim3(256), 0, stream,
                     preds, pc, n, nyb, sboxes, sidx);
  hipLaunchKernelGGL(k_mask, dim3(nw, nw), dim3(64), 0, stream,
                     sboxes, n, thr, M, D1, nw);
  hipLaunchKernelGGL(k_scan, dim3(1), dim3(64), 0, stream,
                     M, D1, n, nw, maxp, sel, cnt);
  hipLaunchKernelGGL(k_emit, dim3((maxp + 255) / 256), dim3(256), 0, stream,
                     preds, sidx, sel, cnt, maxp, out);
}